// Round 1
// baseline (363.507 us; speedup 1.0000x reference)
//
#include <hip/hip_runtime.h>

#define DCH 1024
#define MSLOT 64
#define NTOK 16384

typedef __bf16 bf16x8 __attribute__((ext_vector_type(8)));
typedef float f32x4 __attribute__((ext_vector_type(4)));
typedef unsigned short u16x8 __attribute__((ext_vector_type(8)));
typedef unsigned short u16x4 __attribute__((ext_vector_type(4)));

__device__ __forceinline__ unsigned short f2bf(float f) {
  unsigned u = __float_as_uint(f);
  u += 0x7fffu + ((u >> 16) & 1u);
  return (unsigned short)(u >> 16);
}
__device__ __forceinline__ float bf2f(unsigned short s) {
  return __uint_as_float(((unsigned)s) << 16);
}

__device__ __forceinline__ void gld16(const void* g, void* l) {
  __builtin_amdgcn_global_load_lds((const __attribute__((address_space(1))) void*)g,
                                   (__attribute__((address_space(3))) void*)l, 16, 0, 0);
}

// ---------------------------------------------------------------------------
// prep: Wm = memory @ Wq  (bf16),  P = memory @ Wf2^T (f32),
//       Wf1 -> bf16 copy,  sc[m] = bq . memory[m]
// grid: 64 (Wm) + 64 (P) + 64 (Wf1 conv) + 1 (sc) = 193 blocks x 256
// ---------------------------------------------------------------------------
__global__ __launch_bounds__(256) void prep_kernel(
    const float* __restrict__ memv, const float* __restrict__ Wq,
    const float* __restrict__ Wf, const float* __restrict__ bq,
    unsigned short* __restrict__ Wmb, float* __restrict__ P,
    unsigned short* __restrict__ Wf1b, float* __restrict__ sc) {
  __shared__ float mrows[4][1024];
  __shared__ float red[256];
  const int b = blockIdx.x, tid = threadIdx.x;

  if (b < 128) {
    const int part = b >> 6;   // 0 = Wm, 1 = P
    const int bb = b & 63;
    const int m0 = (bb >> 2) << 2;          // 4 memory rows per block
    const int d = ((bb & 3) << 8) + tid;    // 256 output cols per block
#pragma unroll
    for (int i = 0; i < 16; ++i) {
      int idx = i * 256 + tid;
      mrows[idx >> 10][idx & 1023] = memv[m0 * 1024 + idx];
    }
    __syncthreads();
    float a0 = 0.f, a1 = 0.f, a2 = 0.f, a3 = 0.f;
    if (part == 0) {
      const float* wp = Wq + d;   // Wq[e*1024 + d]
#pragma unroll 4
      for (int e = 0; e < 1024; ++e) {
        float w = wp[e * 1024];
        a0 += mrows[0][e] * w; a1 += mrows[1][e] * w;
        a2 += mrows[2][e] * w; a3 += mrows[3][e] * w;
      }
      Wmb[(m0 + 0) * 1024 + d] = f2bf(a0);
      Wmb[(m0 + 1) * 1024 + d] = f2bf(a1);
      Wmb[(m0 + 2) * 1024 + d] = f2bf(a2);
      Wmb[(m0 + 3) * 1024 + d] = f2bf(a3);
    } else {
      const float* wp = Wf + (size_t)d * 2048 + 1024;  // Wf2 row d
#pragma unroll 4
      for (int c = 0; c < 1024; ++c) {
        float w = wp[c];
        a0 += mrows[0][c] * w; a1 += mrows[1][c] * w;
        a2 += mrows[2][c] * w; a3 += mrows[3][c] * w;
      }
      P[(m0 + 0) * 1024 + d] = a0;
      P[(m0 + 1) * 1024 + d] = a1;
      P[(m0 + 2) * 1024 + d] = a2;
      P[(m0 + 3) * 1024 + d] = a3;
    }
  } else if (b < 192) {
    const int j = b - 128;   // Wf1 -> bf16, 64 blocks, 4096 float4 each
#pragma unroll
    for (int i = 0; i < 16; ++i) {
      int f4 = j * 4096 + i * 256 + tid;
      int row = f4 >> 8, c4 = (f4 & 255) * 4;
      float4 v = *(const float4*)(Wf + (size_t)row * 2048 + c4);
      u16x4 o = {f2bf(v.x), f2bf(v.y), f2bf(v.z), f2bf(v.w)};
      *(u16x4*)(Wf1b + row * 1024 + c4) = o;
    }
  } else {
    // sc[m] = sum_e bq[e] * memory[m][e]
    int m = tid >> 2, q = tid & 3;
    float s = 0.f;
    for (int e = q * 256; e < q * 256 + 256; ++e) s += bq[e] * memv[m * 1024 + e];
    red[tid] = s;
    __syncthreads();
    if (tid < 64) sc[tid] = red[tid * 4] + red[tid * 4 + 1] + red[tid * 4 + 2] + red[tid * 4 + 3];
  }
}

// ---------------------------------------------------------------------------
// xconv: x (f32) -> xb (bf16). 8192 blocks x 256, 8 elems/thread
// ---------------------------------------------------------------------------
__global__ __launch_bounds__(256) void xconv_kernel(const float* __restrict__ x,
                                                    unsigned short* __restrict__ xb) {
  int idx8 = (blockIdx.x * 256 + threadIdx.x) * 8;
  float4 a = *(const float4*)(x + idx8);
  float4 b = *(const float4*)(x + idx8 + 4);
  u16x8 o = {f2bf(a.x), f2bf(a.y), f2bf(a.z), f2bf(a.w),
             f2bf(b.x), f2bf(b.y), f2bf(b.z), f2bf(b.w)};
  *(u16x8*)(xb + idx8) = o;
}

// ---------------------------------------------------------------------------
// sim_topk: sim = xb @ Wmb^T + sc  (128 tok x 64 m per block), then per-token
// top-3 + softmax -> meta float4 {w0,w1,w2, packed idx}
// grid: 128 blocks x 256
// ---------------------------------------------------------------------------
__global__ __launch_bounds__(256) void sim_topk_kernel(
    const unsigned short* __restrict__ xb, const unsigned short* __restrict__ Wmb,
    const float* __restrict__ sc, float4* __restrict__ meta) {
  __shared__ __attribute__((aligned(16))) unsigned short As[128 * 64];
  __shared__ __attribute__((aligned(16))) unsigned short Bs[64 * 64];
  __shared__ float sim_s[128 * 65];
  const int tid = threadIdx.x;
  const int wave = tid >> 6, lane = tid & 63;
  const int tok0 = blockIdx.x * 128;
  const int quad = lane >> 4, cl = lane & 15;

  f32x4 acc[2][4];
#pragma unroll
  for (int i = 0; i < 2; ++i)
#pragma unroll
    for (int j = 0; j < 4; ++j) acc[i][j] = {0.f, 0.f, 0.f, 0.f};

  for (int kt = 0; kt < 16; ++kt) {
    __syncthreads();
#pragma unroll
    for (int i = 0; i < 4; ++i) {
      int ch = (wave * 4 + i) * 64 + lane;
      int row = ch >> 3, cb = (ch & 7) * 8;
      gld16(xb + (size_t)(tok0 + row) * 1024 + kt * 64 + cb, As + ch * 8);
    }
#pragma unroll
    for (int i = 0; i < 2; ++i) {
      int ch = (wave * 2 + i) * 64 + lane;
      int row = ch >> 3, cb = (ch & 7) * 8;
      gld16(Wmb + row * 1024 + kt * 64 + cb, Bs + ch * 8);
    }
    __syncthreads();
    const unsigned short* Ab = As + (wave * 32 + cl) * 64 + quad * 8;
    const unsigned short* Bb = Bs + cl * 64 + quad * 8;
#pragma unroll
    for (int ks = 0; ks < 2; ++ks) {
      bf16x8 a0 = *(const bf16x8*)(Ab + ks * 32);
      bf16x8 a1 = *(const bf16x8*)(Ab + 16 * 64 + ks * 32);
#pragma unroll
      for (int nt = 0; nt < 4; ++nt) {
        bf16x8 bb = *(const bf16x8*)(Bb + nt * 16 * 64 + ks * 32);
        acc[0][nt] = __builtin_amdgcn_mfma_f32_16x16x32_bf16(a0, bb, acc[0][nt], 0, 0, 0);
        acc[1][nt] = __builtin_amdgcn_mfma_f32_16x16x32_bf16(a1, bb, acc[1][nt], 0, 0, 0);
      }
    }
  }
#pragma unroll
  for (int mt = 0; mt < 2; ++mt)
#pragma unroll
    for (int nt = 0; nt < 4; ++nt)
#pragma unroll
      for (int r = 0; r < 4; ++r) {
        int lt = wave * 32 + mt * 16 + quad * 4 + r;
        int mc = nt * 16 + cl;
        sim_s[lt * 65 + mc] = acc[mt][nt][r] + sc[mc];
      }
  __syncthreads();
  if (tid < 128) {
    const float* sp = sim_s + tid * 65;
    float s0 = -1e30f, s1 = -1e30f, s2 = -1e30f;
    int i0 = 0, i1 = 0, i2 = 0;
    for (int m = 0; m < 64; ++m) {
      float v = sp[m];
      if (v > s0) { s2 = s1; i2 = i1; s1 = s0; i1 = i0; s0 = v; i0 = m; }
      else if (v > s1) { s2 = s1; i2 = i1; s1 = v; i1 = m; }
      else if (v > s2) { s2 = v; i2 = m; }
    }
    float e1 = __expf(s1 - s0), e2 = __expf(s2 - s0);
    float inv = 1.f / (1.f + e1 + e2);
    meta[tok0 + tid] = make_float4(inv, e1 * inv, e2 * inv,
                                   __int_as_float(i0 | (i1 << 8) | (i2 << 16)));
  }
}

// ---------------------------------------------------------------------------
// gemm_h: h = xb @ Wf1b^T + bf + sum_k w_k * P[i_k]   -> hb (bf16)
// 128x128 tile, BK=64, 16x16x32 bf16 MFMA, global_load_lds staging (m97 style)
// grid: dim3(8, 128) x 256
// ---------------------------------------------------------------------------
__global__ __launch_bounds__(256) void gemm_h_kernel(
    const unsigned short* __restrict__ xb, const unsigned short* __restrict__ Wf1b,
    const float* __restrict__ P, const float4* __restrict__ meta,
    const float* __restrict__ bfv, unsigned short* __restrict__ hb) {
  __shared__ __attribute__((aligned(16))) unsigned short As[128 * 64];
  __shared__ __attribute__((aligned(16))) unsigned short Bs[128 * 64];
  const int tid = threadIdx.x;
  const int wave = tid >> 6, lane = tid & 63;
  const int d0 = blockIdx.x * 128, tok0 = blockIdx.y * 128;
  const int quad = lane >> 4, cl = lane & 15;
  const int wm = (wave & 1) * 64, wn = (wave >> 1) * 64;

  f32x4 acc[4][4];
#pragma unroll
  for (int i = 0; i < 4; ++i)
#pragma unroll
    for (int j = 0; j < 4; ++j) acc[i][j] = {0.f, 0.f, 0.f, 0.f};

  for (int kt = 0; kt < 16; ++kt) {
    __syncthreads();
#pragma unroll
    for (int i = 0; i < 4; ++i) {
      int ch = (wave * 4 + i) * 64 + lane;
      int row = ch >> 3, cb = (ch & 7) * 8;
      gld16(xb + (size_t)(tok0 + row) * 1024 + kt * 64 + cb, As + ch * 8);
      gld16(Wf1b + (size_t)(d0 + row) * 1024 + kt * 64 + cb, Bs + ch * 8);
    }
    __syncthreads();
    const unsigned short* Ab = As + (wm + cl) * 64 + quad * 8;
    const unsigned short* Bb = Bs + (wn + cl) * 64 + quad * 8;
#pragma unroll
    for (int ks = 0; ks < 2; ++ks) {
      bf16x8 a[4], b[4];
#pragma unroll
      for (int t = 0; t < 4; ++t) a[t] = *(const bf16x8*)(Ab + t * 1024 + ks * 32);
#pragma unroll
      for (int t = 0; t < 4; ++t) b[t] = *(const bf16x8*)(Bb + t * 1024 + ks * 32);
#pragma unroll
      for (int mt = 0; mt < 4; ++mt)
#pragma unroll
        for (int nt = 0; nt < 4; ++nt)
          acc[mt][nt] = __builtin_amdgcn_mfma_f32_16x16x32_bf16(a[mt], b[nt], acc[mt][nt], 0, 0, 0);
    }
  }

  // epilogue: + bf + w0*P[i0] + w1*P[i1] + w2*P[i2], store bf16 h
#pragma unroll
  for (int mt = 0; mt < 4; ++mt) {
#pragma unroll
    for (int r = 0; r < 4; ++r) {
      int row = tok0 + wm + mt * 16 + quad * 4 + r;
      float4 mv = meta[row];
      int pk = __float_as_int(mv.w);
      const float* P0 = P + (pk & 255) * 1024;
      const float* P1 = P + ((pk >> 8) & 255) * 1024;
      const float* P2 = P + ((pk >> 16) & 255) * 1024;
#pragma unroll
      for (int nt = 0; nt < 4; ++nt) {
        int d = d0 + wn + nt * 16 + cl;
        float h = acc[mt][nt][r] + bfv[d] + mv.x * P0[d] + mv.y * P1[d] + mv.z * P2[d];
        hb[(size_t)row * 1024 + d] = f2bf(h);
      }
    }
  }
}

// ---------------------------------------------------------------------------
// ln_relu: per-token LayerNorm (over 1024) + ReLU; one wave per token
// grid: 4096 blocks x 256
// ---------------------------------------------------------------------------
__global__ __launch_bounds__(256) void ln_relu_kernel(
    const unsigned short* __restrict__ hb, const float* __restrict__ gamma,
    const float* __restrict__ beta, float* __restrict__ out) {
  const int tid = threadIdx.x;
  const int wave = tid >> 6, lane = tid & 63;
  const int t = blockIdx.x * 4 + wave;
  const unsigned short* hp = hb + (size_t)t * 1024 + lane * 16;
  u16x8 h0 = *(const u16x8*)(hp);
  u16x8 h1 = *(const u16x8*)(hp + 8);
  float f[16];
#pragma unroll
  for (int j = 0; j < 8; ++j) { f[j] = bf2f(h0[j]); f[8 + j] = bf2f(h1[j]); }
  float s = 0.f, q = 0.f;
#pragma unroll
  for (int j = 0; j < 16; ++j) { s += f[j]; q += f[j] * f[j]; }
#pragma unroll
  for (int off = 32; off; off >>= 1) {
    s += __shfl_xor(s, off);
    q += __shfl_xor(q, off);
  }
  float mean = s * (1.f / 1024.f);
  float var = q * (1.f / 1024.f) - mean * mean;
  float rs = rsqrtf(var + 1e-5f);
  const int dbase = lane * 16;
  float o[16];
#pragma unroll
  for (int j = 0; j < 16; ++j) {
    float v = (f[j] - mean) * rs * gamma[dbase + j] + beta[dbase + j];
    o[j] = fmaxf(v, 0.f);
  }
  float* op = out + (size_t)t * 1024 + dbase;
#pragma unroll
  for (int j4 = 0; j4 < 4; ++j4) {
    float4 v = {o[j4 * 4], o[j4 * 4 + 1], o[j4 * 4 + 2], o[j4 * 4 + 3]};
    *(float4*)(op + j4 * 4) = v;
  }
}

// ---------------------------------------------------------------------------
extern "C" void kernel_launch(void* const* d_in, const int* in_sizes, int n_in,
                              void* d_out, int out_size, void* d_ws, size_t ws_size,
                              hipStream_t stream) {
  const float* x     = (const float*)d_in[0];
  const float* memv  = (const float*)d_in[1];
  const float* Wq    = (const float*)d_in[2];
  const float* bq    = (const float*)d_in[3];
  const float* Wf    = (const float*)d_in[4];
  const float* bfv   = (const float*)d_in[5];
  const float* gamma = (const float*)d_in[6];
  const float* beta  = (const float*)d_in[7];
  float* out = (float*)d_out;
  char* ws = (char*)d_ws;

  unsigned short* Wf1b = (unsigned short*)(ws);              // 2 MB
  unsigned short* Wmb  = (unsigned short*)(ws + 2097152);    // 128 KB
  float*          P    = (float*)(ws + 2228224);             // 256 KB
  float*          sc   = (float*)(ws + 2490368);             // 256 B
  float4*         meta = (float4*)(ws + 2490624);            // 256 KB
  unsigned short* xb   = (unsigned short*)(ws + 2752768);    // 32 MB
  unsigned short* hb   = (unsigned short*)(ws + 36307200);   // 32 MB
  // total ws usage: 69,861,632 bytes

  hipLaunchKernelGGL(prep_kernel, dim3(193), dim3(256), 0, stream,
                     memv, Wq, Wf, bq, Wmb, P, Wf1b, sc);
  hipLaunchKernelGGL(xconv_kernel, dim3(8192), dim3(256), 0, stream, x, xb);
  hipLaunchKernelGGL(sim_topk_kernel, dim3(128), dim3(256), 0, stream,
                     xb, Wmb, sc, meta);
  hipLaunchKernelGGL(gemm_h_kernel, dim3(8, 128), dim3(256), 0, stream,
                     xb, Wf1b, P, meta, bfv, hb);
  hipLaunchKernelGGL(ln_relu_kernel, dim3(4096), dim3(256), 0, stream,
                     hb, gamma, beta, out);
}

// Round 2
// 283.660 us; speedup vs baseline: 1.2815x; 1.2815x over previous
//
#include <hip/hip_runtime.h>

#define DCH 1024
#define MSLOT 64
#define NTOK 16384

typedef __bf16 bf16x8 __attribute__((ext_vector_type(8)));
typedef float f32x4 __attribute__((ext_vector_type(4)));
typedef unsigned short u16x8 __attribute__((ext_vector_type(8)));
typedef unsigned short u16x4 __attribute__((ext_vector_type(4)));

__device__ __forceinline__ unsigned short f2bf(float f) {
  unsigned u = __float_as_uint(f);
  u += 0x7fffu + ((u >> 16) & 1u);
  return (unsigned short)(u >> 16);
}
__device__ __forceinline__ float bf2f(unsigned short s) {
  return __uint_as_float(((unsigned)s) << 16);
}

__device__ __forceinline__ void gld16(const void* g, void* l) {
  __builtin_amdgcn_global_load_lds((const __attribute__((address_space(1))) void*)g,
                                   (__attribute__((address_space(3))) void*)l, 16, 0, 0);
}

// ---------------------------------------------------------------------------
// prep_a: fused big conversion pass.
//   b in [0,8192)     : x (f32) -> xb (bf16), 8 elems/thread
//   b in [8192,8448)  : Wf2 transpose -> Wf2T[c][d] (fp32), 64x64 LDS tiles
//   b in [8448,8512)  : Wf1 -> bf16
//   b == 8512         : sc[m] = bq . memory[m]
// ---------------------------------------------------------------------------
__global__ __launch_bounds__(256) void prep_a_kernel(
    const float* __restrict__ x, unsigned short* __restrict__ xb,
    const float* __restrict__ Wf, float* __restrict__ Wf2T,
    unsigned short* __restrict__ Wf1b,
    const float* __restrict__ bq, const float* __restrict__ memv,
    float* __restrict__ sc) {
  __shared__ float tile[64][65];
  __shared__ float red[256];
  const int b = blockIdx.x, tid = threadIdx.x;

  if (b < 8192) {
    int idx8 = (b * 256 + tid) * 8;
    float4 a = *(const float4*)(x + idx8);
    float4 c = *(const float4*)(x + idx8 + 4);
    u16x8 o = {f2bf(a.x), f2bf(a.y), f2bf(a.z), f2bf(a.w),
               f2bf(c.x), f2bf(c.y), f2bf(c.z), f2bf(c.w)};
    *(u16x8*)(xb + idx8) = o;
  } else if (b < 8448) {
    // transpose Wf2: Wf2T[c][d] = Wf[d][1024+c]
    const int t = b - 8192;
    const int c0 = (t & 15) * 64, d0 = (t >> 4) * 64;
    const int lane = tid & 63, wv = tid >> 6;
#pragma unroll
    for (int i = 0; i < 16; ++i) {
      int r = wv + i * 4;   // row within tile
      tile[r][lane] = Wf[(size_t)(d0 + r) * 2048 + 1024 + c0 + lane];
    }
    __syncthreads();
#pragma unroll
    for (int i = 0; i < 16; ++i) {
      int r = wv + i * 4;
      Wf2T[(size_t)(c0 + r) * 1024 + d0 + lane] = tile[lane][r];
    }
  } else if (b < 8512) {
    const int j = b - 8448;   // Wf1 -> bf16, 64 blocks, 4096 float4 each
#pragma unroll
    for (int i = 0; i < 16; ++i) {
      int f4 = j * 4096 + i * 256 + tid;
      int row = f4 >> 8, c4 = (f4 & 255) * 4;
      float4 v = *(const float4*)(Wf + (size_t)row * 2048 + c4);
      u16x4 o = {f2bf(v.x), f2bf(v.y), f2bf(v.z), f2bf(v.w)};
      *(u16x4*)(Wf1b + row * 1024 + c4) = o;
    }
  } else {
    // sc[m] = sum_e bq[e] * memory[m][e]
    int m = tid >> 2, q = tid & 3;
    float s = 0.f;
    for (int e = q * 256; e < q * 256 + 256; ++e) s += bq[e] * memv[m * 1024 + e];
    red[tid] = s;
    __syncthreads();
    if (tid < 64) sc[tid] = red[tid * 4] + red[tid * 4 + 1] + red[tid * 4 + 2] + red[tid * 4 + 3];
  }
}

// ---------------------------------------------------------------------------
// prep_b: split-K partial GEMMs (M=64, N=1024, K=1024, fp32 VALU).
//   b < 128 : Wm partials (B = Wq, K-major [e][d])
//   else    : P  partials (B = Wf2T, K-major [c][d])
// decomposition: kc(8: 128-e chunks) x dt(4: 256-d tiles) x mg(4: 16-m groups)
// memory operand indexes are wave-uniform -> scalar loads.
// ---------------------------------------------------------------------------
__global__ __launch_bounds__(256) void prep_b_kernel(
    const float* __restrict__ memv, const float* __restrict__ Wq,
    const float* __restrict__ Wf2T,
    float* __restrict__ partWm, float* __restrict__ partP) {
  int b = blockIdx.x;
  const int tid = threadIdx.x;
  const int which = b >> 7;
  b &= 127;
  const int kc = b & 7, dt = (b >> 3) & 3, mg = b >> 5;
  const float* B = which ? Wf2T : Wq;
  float* outp = which ? partP : partWm;
  const int d = dt * 256 + tid;
  const int e0 = kc * 128;
  const int m0 = mg * 16;

  float acc[16];
#pragma unroll
  for (int m = 0; m < 16; ++m) acc[m] = 0.f;

  const float* bp = B + (size_t)e0 * 1024 + d;
  const float* mp = memv + m0 * 1024 + e0;
#pragma unroll 4
  for (int e = 0; e < 128; ++e) {
    float wv = bp[(size_t)e * 1024];
#pragma unroll
    for (int m = 0; m < 16; ++m) acc[m] += mp[m * 1024 + e] * wv;
  }
  float* op = outp + ((size_t)kc * 64 + m0) * 1024 + d;
#pragma unroll
  for (int m = 0; m < 16; ++m) op[m * 1024] = acc[m];
}

// ---------------------------------------------------------------------------
// prep_c: reduce 8 partials. idx < 65536 -> Wmb (bf16); else -> P (fp32)
// grid 512 x 256
// ---------------------------------------------------------------------------
__global__ __launch_bounds__(256) void prep_c_kernel(
    const float* __restrict__ partWm, const float* __restrict__ partP,
    unsigned short* __restrict__ Wmb, float* __restrict__ P) {
  int idx = blockIdx.x * 256 + threadIdx.x;
  if (idx < 65536) {
    float s = 0.f;
#pragma unroll
    for (int k = 0; k < 8; ++k) s += partWm[k * 65536 + idx];
    Wmb[idx] = f2bf(s);
  } else {
    idx -= 65536;
    float s = 0.f;
#pragma unroll
    for (int k = 0; k < 8; ++k) s += partP[k * 65536 + idx];
    P[idx] = s;
  }
}

// ---------------------------------------------------------------------------
// sim_topk: sim = xb @ Wmb^T + sc  (128 tok x 64 m per block), then per-token
// top-3 + softmax -> meta float4 {w0,w1,w2, packed idx}
// grid: 128 blocks x 256
// ---------------------------------------------------------------------------
__global__ __launch_bounds__(256) void sim_topk_kernel(
    const unsigned short* __restrict__ xb, const unsigned short* __restrict__ Wmb,
    const float* __restrict__ sc, float4* __restrict__ meta) {
  __shared__ __attribute__((aligned(16))) unsigned short As[128 * 64];
  __shared__ __attribute__((aligned(16))) unsigned short Bs[64 * 64];
  __shared__ float sim_s[128 * 65];
  const int tid = threadIdx.x;
  const int wave = tid >> 6, lane = tid & 63;
  const int tok0 = blockIdx.x * 128;
  const int quad = lane >> 4, cl = lane & 15;

  f32x4 acc[2][4];
#pragma unroll
  for (int i = 0; i < 2; ++i)
#pragma unroll
    for (int j = 0; j < 4; ++j) acc[i][j] = {0.f, 0.f, 0.f, 0.f};

  for (int kt = 0; kt < 16; ++kt) {
    __syncthreads();
#pragma unroll
    for (int i = 0; i < 4; ++i) {
      int ch = (wave * 4 + i) * 64 + lane;
      int row = ch >> 3, cb = (ch & 7) * 8;
      gld16(xb + (size_t)(tok0 + row) * 1024 + kt * 64 + cb, As + ch * 8);
    }
#pragma unroll
    for (int i = 0; i < 2; ++i) {
      int ch = (wave * 2 + i) * 64 + lane;
      int row = ch >> 3, cb = (ch & 7) * 8;
      gld16(Wmb + row * 1024 + kt * 64 + cb, Bs + ch * 8);
    }
    __syncthreads();
    const unsigned short* Ab = As + (wave * 32 + cl) * 64 + quad * 8;
    const unsigned short* Bb = Bs + cl * 64 + quad * 8;
#pragma unroll
    for (int ks = 0; ks < 2; ++ks) {
      bf16x8 a0 = *(const bf16x8*)(Ab + ks * 32);
      bf16x8 a1 = *(const bf16x8*)(Ab + 16 * 64 + ks * 32);
#pragma unroll
      for (int nt = 0; nt < 4; ++nt) {
        bf16x8 bb = *(const bf16x8*)(Bb + nt * 16 * 64 + ks * 32);
        acc[0][nt] = __builtin_amdgcn_mfma_f32_16x16x32_bf16(a0, bb, acc[0][nt], 0, 0, 0);
        acc[1][nt] = __builtin_amdgcn_mfma_f32_16x16x32_bf16(a1, bb, acc[1][nt], 0, 0, 0);
      }
    }
  }
#pragma unroll
  for (int mt = 0; mt < 2; ++mt)
#pragma unroll
    for (int nt = 0; nt < 4; ++nt)
#pragma unroll
      for (int r = 0; r < 4; ++r) {
        int lt = wave * 32 + mt * 16 + quad * 4 + r;
        int mc = nt * 16 + cl;
        sim_s[lt * 65 + mc] = acc[mt][nt][r] + sc[mc];
      }
  __syncthreads();
  if (tid < 128) {
    const float* sp = sim_s + tid * 65;
    float s0 = -1e30f, s1 = -1e30f, s2 = -1e30f;
    int i0 = 0, i1 = 0, i2 = 0;
    for (int m = 0; m < 64; ++m) {
      float v = sp[m];
      if (v > s0) { s2 = s1; i2 = i1; s1 = s0; i1 = i0; s0 = v; i0 = m; }
      else if (v > s1) { s2 = s1; i2 = i1; s1 = v; i1 = m; }
      else if (v > s2) { s2 = v; i2 = m; }
    }
    float e1 = __expf(s1 - s0), e2 = __expf(s2 - s0);
    float inv = 1.f / (1.f + e1 + e2);
    meta[tok0 + tid] = make_float4(inv, e1 * inv, e2 * inv,
                                   __int_as_float(i0 | (i1 << 8) | (i2 << 16)));
  }
}

// ---------------------------------------------------------------------------
// gemm_h: h = xb @ Wf1b^T + bf + sum_k w_k * P[i_k]   -> hb (bf16)
// 128x128 tile, BK=64, 16x16x32 bf16 MFMA, global_load_lds staging (m97 style)
// grid: dim3(8, 128) x 256
// ---------------------------------------------------------------------------
__global__ __launch_bounds__(256) void gemm_h_kernel(
    const unsigned short* __restrict__ xb, const unsigned short* __restrict__ Wf1b,
    const float* __restrict__ P, const float4* __restrict__ meta,
    const float* __restrict__ bfv, unsigned short* __restrict__ hb) {
  __shared__ __attribute__((aligned(16))) unsigned short As[128 * 64];
  __shared__ __attribute__((aligned(16))) unsigned short Bs[128 * 64];
  const int tid = threadIdx.x;
  const int wave = tid >> 6, lane = tid & 63;
  const int d0 = blockIdx.x * 128, tok0 = blockIdx.y * 128;
  const int quad = lane >> 4, cl = lane & 15;
  const int wm = (wave & 1) * 64, wn = (wave >> 1) * 64;

  f32x4 acc[4][4];
#pragma unroll
  for (int i = 0; i < 4; ++i)
#pragma unroll
    for (int j = 0; j < 4; ++j) acc[i][j] = {0.f, 0.f, 0.f, 0.f};

  for (int kt = 0; kt < 16; ++kt) {
    __syncthreads();
#pragma unroll
    for (int i = 0; i < 4; ++i) {
      int ch = (wave * 4 + i) * 64 + lane;
      int row = ch >> 3, cb = (ch & 7) * 8;
      gld16(xb + (size_t)(tok0 + row) * 1024 + kt * 64 + cb, As + ch * 8);
      gld16(Wf1b + (size_t)(d0 + row) * 1024 + kt * 64 + cb, Bs + ch * 8);
    }
    __syncthreads();
    const unsigned short* Ab = As + (wm + cl) * 64 + quad * 8;
    const unsigned short* Bb = Bs + (wn + cl) * 64 + quad * 8;
#pragma unroll
    for (int ks = 0; ks < 2; ++ks) {
      bf16x8 a[4], b[4];
#pragma unroll
      for (int t = 0; t < 4; ++t) a[t] = *(const bf16x8*)(Ab + t * 1024 + ks * 32);
#pragma unroll
      for (int t = 0; t < 4; ++t) b[t] = *(const bf16x8*)(Bb + t * 1024 + ks * 32);
#pragma unroll
      for (int mt = 0; mt < 4; ++mt)
#pragma unroll
        for (int nt = 0; nt < 4; ++nt)
          acc[mt][nt] = __builtin_amdgcn_mfma_f32_16x16x32_bf16(a[mt], b[nt], acc[mt][nt], 0, 0, 0);
    }
  }

  // epilogue: + bf + w0*P[i0] + w1*P[i1] + w2*P[i2], store bf16 h
#pragma unroll
  for (int mt = 0; mt < 4; ++mt) {
#pragma unroll
    for (int r = 0; r < 4; ++r) {
      int row = tok0 + wm + mt * 16 + quad * 4 + r;
      float4 mv = meta[row];
      int pk = __float_as_int(mv.w);
      const float* P0 = P + (pk & 255) * 1024;
      const float* P1 = P + ((pk >> 8) & 255) * 1024;
      const float* P2 = P + ((pk >> 16) & 255) * 1024;
#pragma unroll
      for (int nt = 0; nt < 4; ++nt) {
        int d = d0 + wn + nt * 16 + cl;
        float h = acc[mt][nt][r] + bfv[d] + mv.x * P0[d] + mv.y * P1[d] + mv.z * P2[d];
        hb[(size_t)row * 1024 + d] = f2bf(h);
      }
    }
  }
}

// ---------------------------------------------------------------------------
// ln_relu: per-token LayerNorm (over 1024) + ReLU; one wave per token
// grid: 4096 blocks x 256
// ---------------------------------------------------------------------------
__global__ __launch_bounds__(256) void ln_relu_kernel(
    const unsigned short* __restrict__ hb, const float* __restrict__ gamma,
    const float* __restrict__ beta, float* __restrict__ out) {
  const int tid = threadIdx.x;
  const int wave = tid >> 6, lane = tid & 63;
  const int t = blockIdx.x * 4 + wave;
  const unsigned short* hp = hb + (size_t)t * 1024 + lane * 16;
  u16x8 h0 = *(const u16x8*)(hp);
  u16x8 h1 = *(const u16x8*)(hp + 8);
  float f[16];
#pragma unroll
  for (int j = 0; j < 8; ++j) { f[j] = bf2f(h0[j]); f[8 + j] = bf2f(h1[j]); }
  float s = 0.f, q = 0.f;
#pragma unroll
  for (int j = 0; j < 16; ++j) { s += f[j]; q += f[j] * f[j]; }
#pragma unroll
  for (int off = 32; off; off >>= 1) {
    s += __shfl_xor(s, off);
    q += __shfl_xor(q, off);
  }
  float mean = s * (1.f / 1024.f);
  float var = q * (1.f / 1024.f) - mean * mean;
  float rs = rsqrtf(var + 1e-5f);
  const int dbase = lane * 16;
  float o[16];
#pragma unroll
  for (int j = 0; j < 16; ++j) {
    float v = (f[j] - mean) * rs * gamma[dbase + j] + beta[dbase + j];
    o[j] = fmaxf(v, 0.f);
  }
  float* op = out + (size_t)t * 1024 + dbase;
#pragma unroll
  for (int j4 = 0; j4 < 4; ++j4) {
    float4 v = {o[j4 * 4], o[j4 * 4 + 1], o[j4 * 4 + 2], o[j4 * 4 + 3]};
    *(float4*)(op + j4 * 4) = v;
  }
}

// ---------------------------------------------------------------------------
extern "C" void kernel_launch(void* const* d_in, const int* in_sizes, int n_in,
                              void* d_out, int out_size, void* d_ws, size_t ws_size,
                              hipStream_t stream) {
  const float* x     = (const float*)d_in[0];
  const float* memv  = (const float*)d_in[1];
  const float* Wq    = (const float*)d_in[2];
  const float* bq    = (const float*)d_in[3];
  const float* Wf    = (const float*)d_in[4];
  const float* bfv   = (const float*)d_in[5];
  const float* gamma = (const float*)d_in[6];
  const float* beta  = (const float*)d_in[7];
  float* out = (float*)d_out;
  char* ws = (char*)d_ws;

  unsigned short* Wf1b   = (unsigned short*)(ws);              // 2 MB
  unsigned short* Wmb    = (unsigned short*)(ws + 2097152);    // 128 KB
  float*          P      = (float*)(ws + 2228224);             // 256 KB
  float*          sc     = (float*)(ws + 2490368);             // 256 B
  float4*         meta   = (float4*)(ws + 2490624);            // 256 KB
  float*          Wf2T   = (float*)(ws + 2752768);             // 4 MB
  float*          partWm = (float*)(ws + 6947072);             // 2 MB
  float*          partP  = (float*)(ws + 9044224);             // 2 MB
  unsigned short* xb     = (unsigned short*)(ws + 11141376);   // 32 MB
  unsigned short* hb     = (unsigned short*)(ws + 44695808);   // 32 MB
  // total ws usage: 78,250,240 bytes

  hipLaunchKernelGGL(prep_a_kernel, dim3(8513), dim3(256), 0, stream,
                     x, xb, Wf, Wf2T, Wf1b, bq, memv, sc);
  hipLaunchKernelGGL(prep_b_kernel, dim3(256), dim3(256), 0, stream,
                     memv, Wq, Wf2T, partWm, partP);
  hipLaunchKernelGGL(prep_c_kernel, dim3(512), dim3(256), 0, stream,
                     partWm, partP, Wmb, P);
  hipLaunchKernelGGL(sim_topk_kernel, dim3(128), dim3(256), 0, stream,
                     xb, Wmb, sc, meta);
  hipLaunchKernelGGL(gemm_h_kernel, dim3(8, 128), dim3(256), 0, stream,
                     xb, Wf1b, P, meta, bfv, hb);
  hipLaunchKernelGGL(ln_relu_kernel, dim3(4096), dim3(256), 0, stream,
                     hb, gamma, beta, out);
}

// Round 3
// 280.858 us; speedup vs baseline: 1.2943x; 1.0100x over previous
//
#include <hip/hip_runtime.h>

#define DCH 1024
#define MSLOT 64
#define NTOK 16384

typedef __bf16 bf16x8 __attribute__((ext_vector_type(8)));
typedef float f32x4 __attribute__((ext_vector_type(4)));
typedef unsigned short u16x8 __attribute__((ext_vector_type(8)));
typedef unsigned short u16x4 __attribute__((ext_vector_type(4)));

__device__ __forceinline__ unsigned short f2bf(float f) {
  unsigned u = __float_as_uint(f);
  u += 0x7fffu + ((u >> 16) & 1u);
  return (unsigned short)(u >> 16);
}
__device__ __forceinline__ float bf2f(unsigned short s) {
  return __uint_as_float(((unsigned)s) << 16);
}

__device__ __forceinline__ void gld16(const void* g, void* l) {
  __builtin_amdgcn_global_load_lds((const __attribute__((address_space(1))) void*)g,
                                   (__attribute__((address_space(3))) void*)l, 16, 0, 0);
}

// ---------------------------------------------------------------------------
// prep_a: fused big conversion pass.
//   b in [0,8192)     : x (f32) -> xb (bf16), 8 elems/thread
//   b in [8192,8448)  : Wf2 transpose -> Wf2T[c][d] (fp32), 64x64 LDS tiles
//   b in [8448,8512)  : Wf1 -> bf16
//   b == 8512         : sc[m] = bq . memory[m]
// ---------------------------------------------------------------------------
__global__ __launch_bounds__(256) void prep_a_kernel(
    const float* __restrict__ x, unsigned short* __restrict__ xb,
    const float* __restrict__ Wf, float* __restrict__ Wf2T,
    unsigned short* __restrict__ Wf1b,
    const float* __restrict__ bq, const float* __restrict__ memv,
    float* __restrict__ sc) {
  __shared__ float tile[64][65];
  __shared__ float red[256];
  const int b = blockIdx.x, tid = threadIdx.x;

  if (b < 8192) {
    int idx8 = (b * 256 + tid) * 8;
    float4 a = *(const float4*)(x + idx8);
    float4 c = *(const float4*)(x + idx8 + 4);
    u16x8 o = {f2bf(a.x), f2bf(a.y), f2bf(a.z), f2bf(a.w),
               f2bf(c.x), f2bf(c.y), f2bf(c.z), f2bf(c.w)};
    *(u16x8*)(xb + idx8) = o;
  } else if (b < 8448) {
    // transpose Wf2: Wf2T[c][d] = Wf[d][1024+c]
    const int t = b - 8192;
    const int c0 = (t & 15) * 64, d0 = (t >> 4) * 64;
    const int lane = tid & 63, wv = tid >> 6;
#pragma unroll
    for (int i = 0; i < 16; ++i) {
      int r = wv + i * 4;   // row within tile
      tile[r][lane] = Wf[(size_t)(d0 + r) * 2048 + 1024 + c0 + lane];
    }
    __syncthreads();
#pragma unroll
    for (int i = 0; i < 16; ++i) {
      int r = wv + i * 4;
      Wf2T[(size_t)(c0 + r) * 1024 + d0 + lane] = tile[lane][r];
    }
  } else if (b < 8512) {
    const int j = b - 8448;   // Wf1 -> bf16, 64 blocks, 4096 float4 each
#pragma unroll
    for (int i = 0; i < 16; ++i) {
      int f4 = j * 4096 + i * 256 + tid;
      int row = f4 >> 8, c4 = (f4 & 255) * 4;
      float4 v = *(const float4*)(Wf + (size_t)row * 2048 + c4);
      u16x4 o = {f2bf(v.x), f2bf(v.y), f2bf(v.z), f2bf(v.w)};
      *(u16x4*)(Wf1b + row * 1024 + c4) = o;
    }
  } else {
    // sc[m] = sum_e bq[e] * memory[m][e]
    int m = tid >> 2, q = tid & 3;
    float s = 0.f;
    for (int e = q * 256; e < q * 256 + 256; ++e) s += bq[e] * memv[m * 1024 + e];
    red[tid] = s;
    __syncthreads();
    if (tid < 64) sc[tid] = red[tid * 4] + red[tid * 4 + 1] + red[tid * 4 + 2] + red[tid * 4 + 3];
  }
}

// ---------------------------------------------------------------------------
// prep_b: split-K partial GEMMs (M=64, N=1024, K=1024, fp32 VALU).
//   b < 128 : Wm partials (B = Wq, K-major [e][d])
//   else    : P  partials (B = Wf2T, K-major [c][d])
// ---------------------------------------------------------------------------
__global__ __launch_bounds__(256) void prep_b_kernel(
    const float* __restrict__ memv, const float* __restrict__ Wq,
    const float* __restrict__ Wf2T,
    float* __restrict__ partWm, float* __restrict__ partP) {
  int b = blockIdx.x;
  const int tid = threadIdx.x;
  const int which = b >> 7;
  b &= 127;
  const int kc = b & 7, dt = (b >> 3) & 3, mg = b >> 5;
  const float* B = which ? Wf2T : Wq;
  float* outp = which ? partP : partWm;
  const int d = dt * 256 + tid;
  const int e0 = kc * 128;
  const int m0 = mg * 16;

  float acc[16];
#pragma unroll
  for (int m = 0; m < 16; ++m) acc[m] = 0.f;

  const float* bp = B + (size_t)e0 * 1024 + d;
  const float* mp = memv + m0 * 1024 + e0;
#pragma unroll 4
  for (int e = 0; e < 128; ++e) {
    float wv = bp[(size_t)e * 1024];
#pragma unroll
    for (int m = 0; m < 16; ++m) acc[m] += mp[m * 1024 + e] * wv;
  }
  float* op = outp + ((size_t)kc * 64 + m0) * 1024 + d;
#pragma unroll
  for (int m = 0; m < 16; ++m) op[m * 1024] = acc[m];
}

// ---------------------------------------------------------------------------
// prep_c: reduce 8 partials. idx < 65536 -> Wmb (bf16); else -> P (fp32)
// ---------------------------------------------------------------------------
__global__ __launch_bounds__(256) void prep_c_kernel(
    const float* __restrict__ partWm, const float* __restrict__ partP,
    unsigned short* __restrict__ Wmb, float* __restrict__ P) {
  int idx = blockIdx.x * 256 + threadIdx.x;
  if (idx < 65536) {
    float s = 0.f;
#pragma unroll
    for (int k = 0; k < 8; ++k) s += partWm[k * 65536 + idx];
    Wmb[idx] = f2bf(s);
  } else {
    idx -= 65536;
    float s = 0.f;
#pragma unroll
    for (int k = 0; k < 8; ++k) s += partP[k * 65536 + idx];
    P[idx] = s;
  }
}

// ---------------------------------------------------------------------------
// sim_topk: sim = xb @ Wmb^T + sc  (64 tok x 64 m per block), then per-token
// top-3 + softmax -> meta float4 {w0,w1,w2, packed idx}
// grid: 256 blocks x 256  (1 block/CU across the whole chip)
// ---------------------------------------------------------------------------
__global__ __launch_bounds__(256) void sim_topk_kernel(
    const unsigned short* __restrict__ xb, const unsigned short* __restrict__ Wmb,
    const float* __restrict__ sc, float4* __restrict__ meta) {
  __shared__ __attribute__((aligned(16))) unsigned short As[64 * 64];
  __shared__ __attribute__((aligned(16))) unsigned short Bs[64 * 64];
  __shared__ float sim_s[64 * 65];
  const int tid = threadIdx.x;
  const int wave = tid >> 6, lane = tid & 63;
  const int tok0 = blockIdx.x * 64;
  const int quad = lane >> 4, cl = lane & 15;

  f32x4 acc[4];
#pragma unroll
  for (int j = 0; j < 4; ++j) acc[j] = {0.f, 0.f, 0.f, 0.f};

  for (int kt = 0; kt < 16; ++kt) {
    __syncthreads();
#pragma unroll
    for (int i = 0; i < 2; ++i) {
      int ch = (wave * 2 + i) * 64 + lane;
      int row = ch >> 3, cb = (ch & 7) * 8;
      gld16(xb + (size_t)(tok0 + row) * 1024 + kt * 64 + cb, As + ch * 8);
      gld16(Wmb + row * 1024 + kt * 64 + cb, Bs + ch * 8);
    }
    __syncthreads();
    const unsigned short* Ab = As + (wave * 16 + cl) * 64 + quad * 8;
    const unsigned short* Bb = Bs + cl * 64 + quad * 8;
#pragma unroll
    for (int ks = 0; ks < 2; ++ks) {
      bf16x8 a = *(const bf16x8*)(Ab + ks * 32);
#pragma unroll
      for (int nt = 0; nt < 4; ++nt) {
        bf16x8 bb = *(const bf16x8*)(Bb + nt * 16 * 64 + ks * 32);
        acc[nt] = __builtin_amdgcn_mfma_f32_16x16x32_bf16(a, bb, acc[nt], 0, 0, 0);
      }
    }
  }
#pragma unroll
  for (int nt = 0; nt < 4; ++nt)
#pragma unroll
    for (int r = 0; r < 4; ++r) {
      int lt = wave * 16 + quad * 4 + r;
      int mc = nt * 16 + cl;
      sim_s[lt * 65 + mc] = acc[nt][r] + sc[mc];
    }
  __syncthreads();
  if (tid < 64) {
    const float* sp = sim_s + tid * 65;
    float s0 = -1e30f, s1 = -1e30f, s2 = -1e30f;
    int i0 = 0, i1 = 0, i2 = 0;
    for (int m = 0; m < 64; ++m) {
      float v = sp[m];
      if (v > s0) { s2 = s1; i2 = i1; s1 = s0; i1 = i0; s0 = v; i0 = m; }
      else if (v > s1) { s2 = s1; i2 = i1; s1 = v; i1 = m; }
      else if (v > s2) { s2 = v; i2 = m; }
    }
    float e1 = __expf(s1 - s0), e2 = __expf(s2 - s0);
    float inv = 1.f / (1.f + e1 + e2);
    meta[tok0 + tid] = make_float4(inv, e1 * inv, e2 * inv,
                                   __int_as_float(i0 | (i1 << 8) | (i2 << 16)));
  }
}

// ---------------------------------------------------------------------------
// gemm_h: hb = xb @ Wf1b^T  (bf16, no epilogue extras)
// 128x128 tile, BK=64, 16x16x32 bf16 MFMA, global_load_lds staging.
// grid: 1024 linear; XCD-aware decode: t = b & 127, dt = b >> 7
//   -> XCD(b)=b%8=t%8: all 8 d-blocks of a token tile share one XCD's L2
//      (per-XCD xb working set = 16 tiles x 256KB = 4MB = L2 size).
// ---------------------------------------------------------------------------
__global__ __launch_bounds__(256) void gemm_h_kernel(
    const unsigned short* __restrict__ xb, const unsigned short* __restrict__ Wf1b,
    unsigned short* __restrict__ hb) {
  __shared__ __attribute__((aligned(16))) unsigned short As[128 * 64];
  __shared__ __attribute__((aligned(16))) unsigned short Bs[128 * 64];
  const int tid = threadIdx.x;
  const int wave = tid >> 6, lane = tid & 63;
  const int b = blockIdx.x;
  const int tok0 = (b & 127) * 128, d0 = (b >> 7) * 128;
  const int quad = lane >> 4, cl = lane & 15;
  const int wm = (wave & 1) * 64, wn = (wave >> 1) * 64;

  f32x4 acc[4][4];
#pragma unroll
  for (int i = 0; i < 4; ++i)
#pragma unroll
    for (int j = 0; j < 4; ++j) acc[i][j] = {0.f, 0.f, 0.f, 0.f};

  for (int kt = 0; kt < 16; ++kt) {
    __syncthreads();
#pragma unroll
    for (int i = 0; i < 4; ++i) {
      int ch = (wave * 4 + i) * 64 + lane;
      int row = ch >> 3, cb = (ch & 7) * 8;
      gld16(xb + (size_t)(tok0 + row) * 1024 + kt * 64 + cb, As + ch * 8);
      gld16(Wf1b + (size_t)(d0 + row) * 1024 + kt * 64 + cb, Bs + ch * 8);
    }
    __syncthreads();
    const unsigned short* Ab = As + (wm + cl) * 64 + quad * 8;
    const unsigned short* Bb = Bs + (wn + cl) * 64 + quad * 8;
#pragma unroll
    for (int ks = 0; ks < 2; ++ks) {
      bf16x8 a[4], bb[4];
#pragma unroll
      for (int t = 0; t < 4; ++t) a[t] = *(const bf16x8*)(Ab + t * 1024 + ks * 32);
#pragma unroll
      for (int t = 0; t < 4; ++t) bb[t] = *(const bf16x8*)(Bb + t * 1024 + ks * 32);
#pragma unroll
      for (int mt = 0; mt < 4; ++mt)
#pragma unroll
        for (int nt = 0; nt < 4; ++nt)
          acc[mt][nt] = __builtin_amdgcn_mfma_f32_16x16x32_bf16(a[mt], bb[nt], acc[mt][nt], 0, 0, 0);
    }
  }

  // epilogue: plain bf16 store (bias + retrieval handled in ln_relu)
#pragma unroll
  for (int mt = 0; mt < 4; ++mt) {
#pragma unroll
    for (int r = 0; r < 4; ++r) {
      int row = tok0 + wm + mt * 16 + quad * 4 + r;
#pragma unroll
      for (int nt = 0; nt < 4; ++nt) {
        int d = d0 + wn + nt * 16 + cl;
        hb[(size_t)row * 1024 + d] = f2bf(acc[mt][nt][r]);
      }
    }
  }
}

// ---------------------------------------------------------------------------
// ln_relu: h = hb + bf + w0*P[i0] + w1*P[i1] + w2*P[i2];
//          out = ReLU(LN(h) * gamma + beta).  One wave per token.
// grid: 4096 blocks x 256
// ---------------------------------------------------------------------------
__global__ __launch_bounds__(256) void ln_relu_kernel(
    const unsigned short* __restrict__ hb, const float* __restrict__ P,
    const float4* __restrict__ meta, const float* __restrict__ bfv,
    const float* __restrict__ gamma, const float* __restrict__ beta,
    float* __restrict__ out) {
  const int tid = threadIdx.x;
  const int wave = tid >> 6, lane = tid & 63;
  const int t = blockIdx.x * 4 + wave;
  const int dbase = lane * 16;

  float4 mv = meta[t];
  int pk = __float_as_int(mv.w);
  const float* P0 = P + (pk & 255) * 1024 + dbase;
  const float* P1 = P + ((pk >> 8) & 255) * 1024 + dbase;
  const float* P2 = P + ((pk >> 16) & 255) * 1024 + dbase;
  const float* bp = bfv + dbase;

  const unsigned short* hp = hb + (size_t)t * 1024 + dbase;
  u16x8 h0 = *(const u16x8*)(hp);
  u16x8 h1 = *(const u16x8*)(hp + 8);
  float f[16];
#pragma unroll
  for (int j = 0; j < 8; ++j) { f[j] = bf2f(h0[j]); f[8 + j] = bf2f(h1[j]); }
#pragma unroll
  for (int j4 = 0; j4 < 4; ++j4) {
    float4 b4 = *(const float4*)(bp + j4 * 4);
    float4 p0 = *(const float4*)(P0 + j4 * 4);
    float4 p1 = *(const float4*)(P1 + j4 * 4);
    float4 p2 = *(const float4*)(P2 + j4 * 4);
    f[j4 * 4 + 0] += b4.x + mv.x * p0.x + mv.y * p1.x + mv.z * p2.x;
    f[j4 * 4 + 1] += b4.y + mv.x * p0.y + mv.y * p1.y + mv.z * p2.y;
    f[j4 * 4 + 2] += b4.z + mv.x * p0.z + mv.y * p1.z + mv.z * p2.z;
    f[j4 * 4 + 3] += b4.w + mv.x * p0.w + mv.y * p1.w + mv.z * p2.w;
  }
  float s = 0.f, q = 0.f;
#pragma unroll
  for (int j = 0; j < 16; ++j) { s += f[j]; q += f[j] * f[j]; }
#pragma unroll
  for (int off = 32; off; off >>= 1) {
    s += __shfl_xor(s, off);
    q += __shfl_xor(q, off);
  }
  float mean = s * (1.f / 1024.f);
  float var = q * (1.f / 1024.f) - mean * mean;
  float rs = rsqrtf(var + 1e-5f);
  float o[16];
#pragma unroll
  for (int j = 0; j < 16; ++j) {
    float v = (f[j] - mean) * rs * gamma[dbase + j] + beta[dbase + j];
    o[j] = fmaxf(v, 0.f);
  }
  float* op = out + (size_t)t * 1024 + dbase;
#pragma unroll
  for (int j4 = 0; j4 < 4; ++j4) {
    float4 v = {o[j4 * 4], o[j4 * 4 + 1], o[j4 * 4 + 2], o[j4 * 4 + 3]};
    *(float4*)(op + j4 * 4) = v;
  }
}

// ---------------------------------------------------------------------------
extern "C" void kernel_launch(void* const* d_in, const int* in_sizes, int n_in,
                              void* d_out, int out_size, void* d_ws, size_t ws_size,
                              hipStream_t stream) {
  const float* x     = (const float*)d_in[0];
  const float* memv  = (const float*)d_in[1];
  const float* Wq    = (const float*)d_in[2];
  const float* bq    = (const float*)d_in[3];
  const float* Wf    = (const float*)d_in[4];
  const float* bfv   = (const float*)d_in[5];
  const float* gamma = (const float*)d_in[6];
  const float* beta  = (const float*)d_in[7];
  float* out = (float*)d_out;
  char* ws = (char*)d_ws;

  unsigned short* Wf1b   = (unsigned short*)(ws);              // 2 MB
  unsigned short* Wmb    = (unsigned short*)(ws + 2097152);    // 128 KB
  float*          P      = (float*)(ws + 2228224);             // 256 KB
  float*          sc     = (float*)(ws + 2490368);             // 256 B
  float4*         meta   = (float4*)(ws + 2490624);            // 256 KB
  float*          Wf2T   = (float*)(ws + 2752768);             // 4 MB
  float*          partWm = (float*)(ws + 6947072);             // 2 MB
  float*          partP  = (float*)(ws + 9044224);             // 2 MB
  unsigned short* xb     = (unsigned short*)(ws + 11141376);   // 32 MB
  unsigned short* hb     = (unsigned short*)(ws + 44695808);   // 32 MB
  // total ws usage: 78,250,240 bytes

  hipLaunchKernelGGL(prep_a_kernel, dim3(8513), dim3(256), 0, stream,
                     x, xb, Wf, Wf2T, Wf1b, bq, memv, sc);
  hipLaunchKernelGGL(prep_b_kernel, dim3(256), dim3(256), 0, stream,
                     memv, Wq, Wf2T, partWm, partP);
  hipLaunchKernelGGL(prep_c_kernel, dim3(512), dim3(256), 0, stream,
                     partWm, partP, Wmb, P);
  hipLaunchKernelGGL(sim_topk_kernel, dim3(256), dim3(256), 0, stream,
                     xb, Wmb, sc, meta);
  hipLaunchKernelGGL(gemm_h_kernel, dim3(1024), dim3(256), 0, stream,
                     xb, Wf1b, hb);
  hipLaunchKernelGGL(ln_relu_kernel, dim3(4096), dim3(256), 0, stream,
                     hb, P, meta, bfv, gamma, beta, out);
}

// Round 4
// 267.045 us; speedup vs baseline: 1.3612x; 1.0517x over previous
//
#include <hip/hip_runtime.h>

#define DCH 1024
#define MSLOT 64
#define NTOK 16384

typedef __bf16 bf16x8 __attribute__((ext_vector_type(8)));
typedef float f32x4 __attribute__((ext_vector_type(4)));
typedef unsigned short u16x8 __attribute__((ext_vector_type(8)));
typedef unsigned short u16x4 __attribute__((ext_vector_type(4)));

__device__ __forceinline__ unsigned short f2bf(float f) {
  unsigned u = __float_as_uint(f);
  u += 0x7fffu + ((u >> 16) & 1u);
  return (unsigned short)(u >> 16);
}
__device__ __forceinline__ float bf2f(unsigned short s) {
  return __uint_as_float(((unsigned)s) << 16);
}

__device__ __forceinline__ void gld16(const void* g, void* l) {
  __builtin_amdgcn_global_load_lds((const __attribute__((address_space(1))) void*)g,
                                   (__attribute__((address_space(3))) void*)l, 16, 0, 0);
}

// ---------------------------------------------------------------------------
// prep_a: fused big conversion pass.
//   b in [0,8192)     : x (f32) -> xb (bf16), 8 elems/thread
//   b in [8192,8448)  : Wf2 transpose -> Wf2T[c][d] (fp32), 64x64 LDS tiles
//   b in [8448,8512)  : Wf1 -> bf16
//   b == 8512         : sc[m] = bq . memory[m]
// ---------------------------------------------------------------------------
__global__ __launch_bounds__(256) void prep_a_kernel(
    const float* __restrict__ x, unsigned short* __restrict__ xb,
    const float* __restrict__ Wf, float* __restrict__ Wf2T,
    unsigned short* __restrict__ Wf1b,
    const float* __restrict__ bq, const float* __restrict__ memv,
    float* __restrict__ sc) {
  __shared__ float tile[64][65];
  __shared__ float red[256];
  const int b = blockIdx.x, tid = threadIdx.x;

  if (b < 8192) {
    int idx8 = (b * 256 + tid) * 8;
    float4 a = *(const float4*)(x + idx8);
    float4 c = *(const float4*)(x + idx8 + 4);
    u16x8 o = {f2bf(a.x), f2bf(a.y), f2bf(a.z), f2bf(a.w),
               f2bf(c.x), f2bf(c.y), f2bf(c.z), f2bf(c.w)};
    *(u16x8*)(xb + idx8) = o;
  } else if (b < 8448) {
    // transpose Wf2: Wf2T[c][d] = Wf[d][1024+c]
    const int t = b - 8192;
    const int c0 = (t & 15) * 64, d0 = (t >> 4) * 64;
    const int lane = tid & 63, wv = tid >> 6;
#pragma unroll
    for (int i = 0; i < 16; ++i) {
      int r = wv + i * 4;   // row within tile
      tile[r][lane] = Wf[(size_t)(d0 + r) * 2048 + 1024 + c0 + lane];
    }
    __syncthreads();
#pragma unroll
    for (int i = 0; i < 16; ++i) {
      int r = wv + i * 4;
      Wf2T[(size_t)(c0 + r) * 1024 + d0 + lane] = tile[lane][r];
    }
  } else if (b < 8512) {
    const int j = b - 8448;   // Wf1 -> bf16, 64 blocks, 4096 float4 each
#pragma unroll
    for (int i = 0; i < 16; ++i) {
      int f4 = j * 4096 + i * 256 + tid;
      int row = f4 >> 8, c4 = (f4 & 255) * 4;
      float4 v = *(const float4*)(Wf + (size_t)row * 2048 + c4);
      u16x4 o = {f2bf(v.x), f2bf(v.y), f2bf(v.z), f2bf(v.w)};
      *(u16x4*)(Wf1b + row * 1024 + c4) = o;
    }
  } else {
    // sc[m] = sum_e bq[e] * memory[m][e]
    int m = tid >> 2, q = tid & 3;
    float s = 0.f;
    for (int e = q * 256; e < q * 256 + 256; ++e) s += bq[e] * memv[m * 1024 + e];
    red[tid] = s;
    __syncthreads();
    if (tid < 64) sc[tid] = red[tid * 4] + red[tid * 4 + 1] + red[tid * 4 + 2] + red[tid * 4 + 3];
  }
}

// ---------------------------------------------------------------------------
// prep_b: split-K partial GEMMs (M=64, N=1024, K=1024, fp32 VALU).
//   b < 128 : Wm partials (B = Wq, K-major [e][d])
//   else    : P  partials (B = Wf2T, K-major [c][d])
// ---------------------------------------------------------------------------
__global__ __launch_bounds__(256) void prep_b_kernel(
    const float* __restrict__ memv, const float* __restrict__ Wq,
    const float* __restrict__ Wf2T,
    float* __restrict__ partWm, float* __restrict__ partP) {
  int b = blockIdx.x;
  const int tid = threadIdx.x;
  const int which = b >> 7;
  b &= 127;
  const int kc = b & 7, dt = (b >> 3) & 3, mg = b >> 5;
  const float* B = which ? Wf2T : Wq;
  float* outp = which ? partP : partWm;
  const int d = dt * 256 + tid;
  const int e0 = kc * 128;
  const int m0 = mg * 16;

  float acc[16];
#pragma unroll
  for (int m = 0; m < 16; ++m) acc[m] = 0.f;

  const float* bp = B + (size_t)e0 * 1024 + d;
  const float* mp = memv + m0 * 1024 + e0;
#pragma unroll 4
  for (int e = 0; e < 128; ++e) {
    float wv = bp[(size_t)e * 1024];
#pragma unroll
    for (int m = 0; m < 16; ++m) acc[m] += mp[m * 1024 + e] * wv;
  }
  float* op = outp + ((size_t)kc * 64 + m0) * 1024 + d;
#pragma unroll
  for (int m = 0; m < 16; ++m) op[m * 1024] = acc[m];
}

// ---------------------------------------------------------------------------
// prep_c: reduce 8 partials. idx < 65536 -> Wmb (bf16); else -> P (fp32)
// ---------------------------------------------------------------------------
__global__ __launch_bounds__(256) void prep_c_kernel(
    const float* __restrict__ partWm, const float* __restrict__ partP,
    unsigned short* __restrict__ Wmb, float* __restrict__ P) {
  int idx = blockIdx.x * 256 + threadIdx.x;
  if (idx < 65536) {
    float s = 0.f;
#pragma unroll
    for (int k = 0; k < 8; ++k) s += partWm[k * 65536 + idx];
    Wmb[idx] = f2bf(s);
  } else {
    idx -= 65536;
    float s = 0.f;
#pragma unroll
    for (int k = 0; k < 8; ++k) s += partP[k * 65536 + idx];
    P[idx] = s;
  }
}

// ---------------------------------------------------------------------------
// sim_topk: sim = xb @ Wmb^T + sc  (64 tok x 64 m per block), then per-token
// top-3 + softmax -> meta float4 {w0,w1,w2, packed idx}
// grid: 256 blocks x 256
// ---------------------------------------------------------------------------
__global__ __launch_bounds__(256) void sim_topk_kernel(
    const unsigned short* __restrict__ xb, const unsigned short* __restrict__ Wmb,
    const float* __restrict__ sc, float4* __restrict__ meta) {
  __shared__ __attribute__((aligned(16))) unsigned short As[64 * 64];
  __shared__ __attribute__((aligned(16))) unsigned short Bs[64 * 64];
  __shared__ float sim_s[64 * 65];
  const int tid = threadIdx.x;
  const int wave = tid >> 6, lane = tid & 63;
  const int tok0 = blockIdx.x * 64;
  const int quad = lane >> 4, cl = lane & 15;

  f32x4 acc[4];
#pragma unroll
  for (int j = 0; j < 4; ++j) acc[j] = {0.f, 0.f, 0.f, 0.f};

  for (int kt = 0; kt < 16; ++kt) {
    __syncthreads();
#pragma unroll
    for (int i = 0; i < 2; ++i) {
      int ch = (wave * 2 + i) * 64 + lane;
      int row = ch >> 3, cb = (ch & 7) * 8;
      gld16(xb + (size_t)(tok0 + row) * 1024 + kt * 64 + cb, As + ch * 8);
      gld16(Wmb + row * 1024 + kt * 64 + cb, Bs + ch * 8);
    }
    __syncthreads();
    const unsigned short* Ab = As + (wave * 16 + cl) * 64 + quad * 8;
    const unsigned short* Bb = Bs + cl * 64 + quad * 8;
#pragma unroll
    for (int ks = 0; ks < 2; ++ks) {
      bf16x8 a = *(const bf16x8*)(Ab + ks * 32);
#pragma unroll
      for (int nt = 0; nt < 4; ++nt) {
        bf16x8 bb = *(const bf16x8*)(Bb + nt * 16 * 64 + ks * 32);
        acc[nt] = __builtin_amdgcn_mfma_f32_16x16x32_bf16(a, bb, acc[nt], 0, 0, 0);
      }
    }
  }
#pragma unroll
  for (int nt = 0; nt < 4; ++nt)
#pragma unroll
    for (int r = 0; r < 4; ++r) {
      int lt = wave * 16 + quad * 4 + r;
      int mc = nt * 16 + cl;
      sim_s[lt * 65 + mc] = acc[nt][r] + sc[mc];
    }
  __syncthreads();
  if (tid < 64) {
    const float* sp = sim_s + tid * 65;
    float s0 = -1e30f, s1 = -1e30f, s2 = -1e30f;
    int i0 = 0, i1 = 0, i2 = 0;
    for (int m = 0; m < 64; ++m) {
      float v = sp[m];
      if (v > s0) { s2 = s1; i2 = i1; s1 = s0; i1 = i0; s0 = v; i0 = m; }
      else if (v > s1) { s2 = s1; i2 = i1; s1 = v; i1 = m; }
      else if (v > s2) { s2 = v; i2 = m; }
    }
    float e1 = __expf(s1 - s0), e2 = __expf(s2 - s0);
    float inv = 1.f / (1.f + e1 + e2);
    meta[tok0 + tid] = make_float4(inv, e1 * inv, e2 * inv,
                                   __int_as_float(i0 | (i1 << 8) | (i2 << 16)));
  }
}

// ---------------------------------------------------------------------------
// gemm_h: hb = xb @ Wf1b^T  (bf16)
// 256(tok) x 128(d) tile, BK=64: stages 48KB/kt per block (vs 64KB for two
// 128x128 blocks) -> total L2-side staging traffic 512->384 MB, and 64
// MFMA/wave per barrier-drain (2x amortization of the vmcnt(0) stall).
// 512 blocks, 2 blocks/CU = 1 full generation.
// XCD swizzle: tok-tile = b & 63, dt = b >> 6 -> all 8 d-blocks of a token
// tile land on XCD (b%8) = (tok-tile%8); per-XCD xb set = 8 x 512KB = 4MB.
// ---------------------------------------------------------------------------
__global__ __launch_bounds__(256, 2) void gemm_h_kernel(
    const unsigned short* __restrict__ xb, const unsigned short* __restrict__ Wf1b,
    unsigned short* __restrict__ hb) {
  __shared__ __attribute__((aligned(16))) unsigned short As[256 * 64];
  __shared__ __attribute__((aligned(16))) unsigned short Bs[128 * 64];
  const int tid = threadIdx.x;
  const int wave = tid >> 6, lane = tid & 63;
  const int b = blockIdx.x;
  const int tok0 = (b & 63) * 256, d0 = (b >> 6) * 128;
  const int quad = lane >> 4, cl = lane & 15;
  const int wm = wave * 64;   // each wave owns 64 token rows, all 128 d cols

  f32x4 acc[4][8];
#pragma unroll
  for (int i = 0; i < 4; ++i)
#pragma unroll
    for (int j = 0; j < 8; ++j) acc[i][j] = {0.f, 0.f, 0.f, 0.f};

  for (int kt = 0; kt < 16; ++kt) {
    __syncthreads();
#pragma unroll
    for (int i = 0; i < 8; ++i) {   // A: 256 rows x 64 cols = 2048 chunks
      int ch = (wave * 8 + i) * 64 + lane;
      int row = ch >> 3, cb = (ch & 7) * 8;
      gld16(xb + (size_t)(tok0 + row) * 1024 + kt * 64 + cb, As + ch * 8);
    }
#pragma unroll
    for (int i = 0; i < 4; ++i) {   // B: 128 rows x 64 cols = 1024 chunks
      int ch = (wave * 4 + i) * 64 + lane;
      int row = ch >> 3, cb = (ch & 7) * 8;
      gld16(Wf1b + (size_t)(d0 + row) * 1024 + kt * 64 + cb, Bs + ch * 8);
    }
    __syncthreads();
    const unsigned short* Ab = As + (wm + cl) * 64 + quad * 8;
    const unsigned short* Bb = Bs + cl * 64 + quad * 8;
#pragma unroll
    for (int ks = 0; ks < 2; ++ks) {
      bf16x8 a[4], bb[8];
#pragma unroll
      for (int t = 0; t < 4; ++t) a[t] = *(const bf16x8*)(Ab + t * 1024 + ks * 32);
#pragma unroll
      for (int t = 0; t < 8; ++t) bb[t] = *(const bf16x8*)(Bb + t * 1024 + ks * 32);
#pragma unroll
      for (int mt = 0; mt < 4; ++mt)
#pragma unroll
        for (int nt = 0; nt < 8; ++nt)
          acc[mt][nt] = __builtin_amdgcn_mfma_f32_16x16x32_bf16(a[mt], bb[nt], acc[mt][nt], 0, 0, 0);
    }
  }

  // epilogue: plain bf16 store (bias + retrieval handled in ln_relu)
#pragma unroll
  for (int mt = 0; mt < 4; ++mt) {
#pragma unroll
    for (int r = 0; r < 4; ++r) {
      int row = tok0 + wm + mt * 16 + quad * 4 + r;
#pragma unroll
      for (int nt = 0; nt < 8; ++nt) {
        int d = d0 + nt * 16 + cl;
        hb[(size_t)row * 1024 + d] = f2bf(acc[mt][nt][r]);
      }
    }
  }
}

// ---------------------------------------------------------------------------
// ln_relu: h = hb + bf + w0*P[i0] + w1*P[i1] + w2*P[i2];
//          out = ReLU(LN(h) * gamma + beta).  One wave per token.
// grid: 4096 blocks x 256
// ---------------------------------------------------------------------------
__global__ __launch_bounds__(256) void ln_relu_kernel(
    const unsigned short* __restrict__ hb, const float* __restrict__ P,
    const float4* __restrict__ meta, const float* __restrict__ bfv,
    const float* __restrict__ gamma, const float* __restrict__ beta,
    float* __restrict__ out) {
  const int tid = threadIdx.x;
  const int wave = tid >> 6, lane = tid & 63;
  const int t = blockIdx.x * 4 + wave;
  const int dbase = lane * 16;

  float4 mv = meta[t];
  int pk = __float_as_int(mv.w);
  const float* P0 = P + (pk & 255) * 1024 + dbase;
  const float* P1 = P + ((pk >> 8) & 255) * 1024 + dbase;
  const float* P2 = P + ((pk >> 16) & 255) * 1024 + dbase;
  const float* bp = bfv + dbase;

  const unsigned short* hp = hb + (size_t)t * 1024 + dbase;
  u16x8 h0 = *(const u16x8*)(hp);
  u16x8 h1 = *(const u16x8*)(hp + 8);
  float f[16];
#pragma unroll
  for (int j = 0; j < 8; ++j) { f[j] = bf2f(h0[j]); f[8 + j] = bf2f(h1[j]); }
#pragma unroll
  for (int j4 = 0; j4 < 4; ++j4) {
    float4 b4 = *(const float4*)(bp + j4 * 4);
    float4 p0 = *(const float4*)(P0 + j4 * 4);
    float4 p1 = *(const float4*)(P1 + j4 * 4);
    float4 p2 = *(const float4*)(P2 + j4 * 4);
    f[j4 * 4 + 0] += b4.x + mv.x * p0.x + mv.y * p1.x + mv.z * p2.x;
    f[j4 * 4 + 1] += b4.y + mv.x * p0.y + mv.y * p1.y + mv.z * p2.y;
    f[j4 * 4 + 2] += b4.z + mv.x * p0.z + mv.y * p1.z + mv.z * p2.z;
    f[j4 * 4 + 3] += b4.w + mv.x * p0.w + mv.y * p1.w + mv.z * p2.w;
  }
  float s = 0.f, q = 0.f;
#pragma unroll
  for (int j = 0; j < 16; ++j) { s += f[j]; q += f[j] * f[j]; }
#pragma unroll
  for (int off = 32; off; off >>= 1) {
    s += __shfl_xor(s, off);
    q += __shfl_xor(q, off);
  }
  float mean = s * (1.f / 1024.f);
  float var = q * (1.f / 1024.f) - mean * mean;
  float rs = rsqrtf(var + 1e-5f);
  float o[16];
#pragma unroll
  for (int j = 0; j < 16; ++j) {
    float v = (f[j] - mean) * rs * gamma[dbase + j] + beta[dbase + j];
    o[j] = fmaxf(v, 0.f);
  }
  float* op = out + (size_t)t * 1024 + dbase;
#pragma unroll
  for (int j4 = 0; j4 < 4; ++j4) {
    float4 v = {o[j4 * 4], o[j4 * 4 + 1], o[j4 * 4 + 2], o[j4 * 4 + 3]};
    *(float4*)(op + j4 * 4) = v;
  }
}

// ---------------------------------------------------------------------------
extern "C" void kernel_launch(void* const* d_in, const int* in_sizes, int n_in,
                              void* d_out, int out_size, void* d_ws, size_t ws_size,
                              hipStream_t stream) {
  const float* x     = (const float*)d_in[0];
  const float* memv  = (const float*)d_in[1];
  const float* Wq    = (const float*)d_in[2];
  const float* bq    = (const float*)d_in[3];
  const float* Wf    = (const float*)d_in[4];
  const float* bfv   = (const float*)d_in[5];
  const float* gamma = (const float*)d_in[6];
  const float* beta  = (const float*)d_in[7];
  float* out = (float*)d_out;
  char* ws = (char*)d_ws;

  unsigned short* Wf1b   = (unsigned short*)(ws);              // 2 MB
  unsigned short* Wmb    = (unsigned short*)(ws + 2097152);    // 128 KB
  float*          P      = (float*)(ws + 2228224);             // 256 KB
  float*          sc     = (float*)(ws + 2490368);             // 256 B
  float4*         meta   = (float4*)(ws + 2490624);            // 256 KB
  float*          Wf2T   = (float*)(ws + 2752768);             // 4 MB
  float*          partWm = (float*)(ws + 6947072);             // 2 MB
  float*          partP  = (float*)(ws + 9044224);             // 2 MB
  unsigned short* xb     = (unsigned short*)(ws + 11141376);   // 32 MB
  unsigned short* hb     = (unsigned short*)(ws + 44695808);   // 32 MB
  // total ws usage: 78,250,240 bytes

  hipLaunchKernelGGL(prep_a_kernel, dim3(8513), dim3(256), 0, stream,
                     x, xb, Wf, Wf2T, Wf1b, bq, memv, sc);
  hipLaunchKernelGGL(prep_b_kernel, dim3(256), dim3(256), 0, stream,
                     memv, Wq, Wf2T, partWm, partP);
  hipLaunchKernelGGL(prep_c_kernel, dim3(512), dim3(256), 0, stream,
                     partWm, partP, Wmb, P);
  hipLaunchKernelGGL(sim_topk_kernel, dim3(256), dim3(256), 0, stream,
                     xb, Wmb, sc, meta);
  hipLaunchKernelGGL(gemm_h_kernel, dim3(512), dim3(256), 0, stream,
                     xb, Wf1b, hb);
  hipLaunchKernelGGL(ln_relu_kernel, dim3(4096), dim3(256), 0, stream,
                     hb, P, meta, bfv, gamma, beta, out);
}

// Round 5
// 259.304 us; speedup vs baseline: 1.4019x; 1.0299x over previous
//
#include <hip/hip_runtime.h>

#define DCH 1024
#define MSLOT 64
#define NTOK 16384

typedef __bf16 bf16x8 __attribute__((ext_vector_type(8)));
typedef float f32x4 __attribute__((ext_vector_type(4)));
typedef unsigned short u16x8 __attribute__((ext_vector_type(8)));
typedef unsigned short u16x4 __attribute__((ext_vector_type(4)));

__device__ __forceinline__ unsigned short f2bf(float f) {
  unsigned u = __float_as_uint(f);
  u += 0x7fffu + ((u >> 16) & 1u);
  return (unsigned short)(u >> 16);
}
__device__ __forceinline__ float bf2f(unsigned short s) {
  return __uint_as_float(((unsigned)s) << 16);
}

__device__ __forceinline__ void gld16(const void* g, void* l) {
  __builtin_amdgcn_global_load_lds((const __attribute__((address_space(1))) void*)g,
                                   (__attribute__((address_space(3))) void*)l, 16, 0, 0);
}

// ---------------------------------------------------------------------------
// prep_a: fused big conversion pass.
//   b in [0,16384)      : x (f32) -> xb (bf16), one float4 per thread
//                         (16B-contiguous per lane load, 8B store — m13 pattern)
//   b in [16384,16640)  : Wf2 transpose -> Wf2T[c][d] (fp32), 64x64 LDS tiles
//   b in [16640,16704)  : Wf1 -> bf16
//   b == 16704          : sc[m] = bq . memory[m]
// ---------------------------------------------------------------------------
__global__ __launch_bounds__(256) void prep_a_kernel(
    const float* __restrict__ x, unsigned short* __restrict__ xb,
    const float* __restrict__ Wf, float* __restrict__ Wf2T,
    unsigned short* __restrict__ Wf1b,
    const float* __restrict__ bq, const float* __restrict__ memv,
    float* __restrict__ sc) {
  __shared__ float tile[64][65];
  __shared__ float red[256];
  const int b = blockIdx.x, tid = threadIdx.x;

  if (b < 16384) {
    int idx4 = (b * 256 + tid) * 4;
    float4 a = *(const float4*)(x + idx4);
    u16x4 o = {f2bf(a.x), f2bf(a.y), f2bf(a.z), f2bf(a.w)};
    *(u16x4*)(xb + idx4) = o;
  } else if (b < 16640) {
    // transpose Wf2: Wf2T[c][d] = Wf[d][1024+c]
    const int t = b - 16384;
    const int c0 = (t & 15) * 64, d0 = (t >> 4) * 64;
    const int lane = tid & 63, wv = tid >> 6;
#pragma unroll
    for (int i = 0; i < 16; ++i) {
      int r = wv + i * 4;   // row within tile
      tile[r][lane] = Wf[(size_t)(d0 + r) * 2048 + 1024 + c0 + lane];
    }
    __syncthreads();
#pragma unroll
    for (int i = 0; i < 16; ++i) {
      int r = wv + i * 4;
      Wf2T[(size_t)(c0 + r) * 1024 + d0 + lane] = tile[lane][r];
    }
  } else if (b < 16704) {
    const int j = b - 16640;   // Wf1 -> bf16, 64 blocks, 4096 float4 each
#pragma unroll
    for (int i = 0; i < 16; ++i) {
      int f4 = j * 4096 + i * 256 + tid;
      int row = f4 >> 8, c4 = (f4 & 255) * 4;
      float4 v = *(const float4*)(Wf + (size_t)row * 2048 + c4);
      u16x4 o = {f2bf(v.x), f2bf(v.y), f2bf(v.z), f2bf(v.w)};
      *(u16x4*)(Wf1b + row * 1024 + c4) = o;
    }
  } else {
    // sc[m] = sum_e bq[e] * memory[m][e]
    int m = tid >> 2, q = tid & 3;
    float s = 0.f;
    for (int e = q * 256; e < q * 256 + 256; ++e) s += bq[e] * memv[m * 1024 + e];
    red[tid] = s;
    __syncthreads();
    if (tid < 64) sc[tid] = red[tid * 4] + red[tid * 4 + 1] + red[tid * 4 + 2] + red[tid * 4 + 3];
  }
}

// ---------------------------------------------------------------------------
// prep_b: split-K partial GEMMs (M=64, N=1024, K=1024, fp32 VALU).
// ---------------------------------------------------------------------------
__global__ __launch_bounds__(256) void prep_b_kernel(
    const float* __restrict__ memv, const float* __restrict__ Wq,
    const float* __restrict__ Wf2T,
    float* __restrict__ partWm, float* __restrict__ partP) {
  int b = blockIdx.x;
  const int tid = threadIdx.x;
  const int which = b >> 7;
  b &= 127;
  const int kc = b & 7, dt = (b >> 3) & 3, mg = b >> 5;
  const float* B = which ? Wf2T : Wq;
  float* outp = which ? partP : partWm;
  const int d = dt * 256 + tid;
  const int e0 = kc * 128;
  const int m0 = mg * 16;

  float acc[16];
#pragma unroll
  for (int m = 0; m < 16; ++m) acc[m] = 0.f;

  const float* bp = B + (size_t)e0 * 1024 + d;
  const float* mp = memv + m0 * 1024 + e0;
#pragma unroll 4
  for (int e = 0; e < 128; ++e) {
    float wv = bp[(size_t)e * 1024];
#pragma unroll
    for (int m = 0; m < 16; ++m) acc[m] += mp[m * 1024 + e] * wv;
  }
  float* op = outp + ((size_t)kc * 64 + m0) * 1024 + d;
#pragma unroll
  for (int m = 0; m < 16; ++m) op[m * 1024] = acc[m];
}

// ---------------------------------------------------------------------------
// prep_c: reduce 8 partials. idx < 65536 -> Wmb (bf16); else -> P (fp32)
// ---------------------------------------------------------------------------
__global__ __launch_bounds__(256) void prep_c_kernel(
    const float* __restrict__ partWm, const float* __restrict__ partP,
    unsigned short* __restrict__ Wmb, float* __restrict__ P) {
  int idx = blockIdx.x * 256 + threadIdx.x;
  if (idx < 65536) {
    float s = 0.f;
#pragma unroll
    for (int k = 0; k < 8; ++k) s += partWm[k * 65536 + idx];
    Wmb[idx] = f2bf(s);
  } else {
    idx -= 65536;
    float s = 0.f;
#pragma unroll
    for (int k = 0; k < 8; ++k) s += partP[k * 65536 + idx];
    P[idx] = s;
  }
}

// ---------------------------------------------------------------------------
// sim_topk: sim = xb @ Wmb^T + sc  (64 tok x 64 m per block), then per-token
// top-3 + softmax -> meta.  XOR-swizzled LDS (see gemm_h comment).
// grid: 256 blocks x 256
// ---------------------------------------------------------------------------
__global__ __launch_bounds__(256) void sim_topk_kernel(
    const unsigned short* __restrict__ xb, const unsigned short* __restrict__ Wmb,
    const float* __restrict__ sc, float4* __restrict__ meta) {
  __shared__ __attribute__((aligned(16))) unsigned short As[64 * 64];
  __shared__ __attribute__((aligned(16))) unsigned short Bs[64 * 64];
  __shared__ float sim_s[64 * 65];
  const int tid = threadIdx.x;
  const int wave = tid >> 6, lane = tid & 63;
  const int tok0 = blockIdx.x * 64;
  const int quad = lane >> 4, cl = lane & 15;
  const int sw = ((lane & 7) ^ (lane >> 3)) * 8;    // staging swizzle (shorts)
  const int cx0 = ((quad) ^ (cl & 7)) * 8;          // read swizzle ks=0
  const int cx1 = ((quad + 4) ^ (cl & 7)) * 8;      // read swizzle ks=1

  f32x4 acc[4];
#pragma unroll
  for (int j = 0; j < 4; ++j) acc[j] = {0.f, 0.f, 0.f, 0.f};

  for (int kt = 0; kt < 16; ++kt) {
    __syncthreads();
#pragma unroll
    for (int i = 0; i < 2; ++i) {
      int ch = (wave * 2 + i) * 64 + lane;
      int row = ch >> 3;
      gld16(xb + (size_t)(tok0 + row) * 1024 + kt * 64 + sw, As + ch * 8);
      gld16(Wmb + row * 1024 + kt * 64 + sw, Bs + ch * 8);
    }
    __syncthreads();
#pragma unroll
    for (int ks = 0; ks < 2; ++ks) {
      const int cx = ks ? cx1 : cx0;
      bf16x8 a = *(const bf16x8*)(As + (wave * 16 + cl) * 64 + cx);
#pragma unroll
      for (int nt = 0; nt < 4; ++nt) {
        bf16x8 bb = *(const bf16x8*)(Bs + (cl + nt * 16) * 64 + cx);
        acc[nt] = __builtin_amdgcn_mfma_f32_16x16x32_bf16(a, bb, acc[nt], 0, 0, 0);
      }
    }
  }
#pragma unroll
  for (int nt = 0; nt < 4; ++nt)
#pragma unroll
    for (int r = 0; r < 4; ++r) {
      int lt = wave * 16 + quad * 4 + r;
      int mc = nt * 16 + cl;
      sim_s[lt * 65 + mc] = acc[nt][r] + sc[mc];
    }
  __syncthreads();
  if (tid < 64) {
    const float* sp = sim_s + tid * 65;
    float s0 = -1e30f, s1 = -1e30f, s2 = -1e30f;
    int i0 = 0, i1 = 0, i2 = 0;
    for (int m = 0; m < 64; ++m) {
      float v = sp[m];
      if (v > s0) { s2 = s1; i2 = i1; s1 = s0; i1 = i0; s0 = v; i0 = m; }
      else if (v > s1) { s2 = s1; i2 = i1; s1 = v; i1 = m; }
      else if (v > s2) { s2 = v; i2 = m; }
    }
    float e1 = __expf(s1 - s0), e2 = __expf(s2 - s0);
    float inv = 1.f / (1.f + e1 + e2);
    meta[tok0 + tid] = make_float4(inv, e1 * inv, e2 * inv,
                                   __int_as_float(i0 | (i1 << 8) | (i2 << 16)));
  }
}

// ---------------------------------------------------------------------------
// gemm_h: hb = xb @ Wf1b^T  (bf16)
// 256(tok) x 128(d) tile, BK=64, XOR-swizzled LDS layout:
//   row stride 64 shorts = 128 B = 32 banks, so un-swizzled fragment reads
//   put all 16 cl-lanes of a quad on the same 4 banks (16-way conflict,
//   9.4M SQ_LDS_BANK_CONFLICT in R4). Since global_load_lds writes at
//   wave-uniform-base + lane*16, swizzle the GLOBAL source column instead:
//   LDS chunk (row, lane&7) holds logical K-chunk (lane&7)^(lane>>3 & 7);
//   reads use physical chunk (quad+4ks)^(cl&7)  -> 2 lanes/bank-group = free.
// grid 512 linear, XCD swizzle: tok-tile = b & 63, dt = b >> 6.
// ---------------------------------------------------------------------------
__global__ __launch_bounds__(256, 2) void gemm_h_kernel(
    const unsigned short* __restrict__ xb, const unsigned short* __restrict__ Wf1b,
    unsigned short* __restrict__ hb) {
  __shared__ __attribute__((aligned(16))) unsigned short As[256 * 64];
  __shared__ __attribute__((aligned(16))) unsigned short Bs[128 * 64];
  const int tid = threadIdx.x;
  const int wave = tid >> 6, lane = tid & 63;
  const int b = blockIdx.x;
  const int tok0 = (b & 63) * 256, d0 = (b >> 6) * 128;
  const int quad = lane >> 4, cl = lane & 15;
  const int wm = wave * 64;   // each wave owns 64 token rows, all 128 d cols
  const int sw = ((lane & 7) ^ (lane >> 3)) * 8;    // staging swizzle (shorts)
  const int cx0 = ((quad) ^ (cl & 7)) * 8;
  const int cx1 = ((quad + 4) ^ (cl & 7)) * 8;

  f32x4 acc[4][8];
#pragma unroll
  for (int i = 0; i < 4; ++i)
#pragma unroll
    for (int j = 0; j < 8; ++j) acc[i][j] = {0.f, 0.f, 0.f, 0.f};

  for (int kt = 0; kt < 16; ++kt) {
    __syncthreads();
#pragma unroll
    for (int i = 0; i < 8; ++i) {   // A: 256 rows x 64 cols = 2048 chunks
      int ch = (wave * 8 + i) * 64 + lane;
      int row = ch >> 3;
      gld16(xb + (size_t)(tok0 + row) * 1024 + kt * 64 + sw, As + ch * 8);
    }
#pragma unroll
    for (int i = 0; i < 4; ++i) {   // B: 128 rows x 64 cols = 1024 chunks
      int ch = (wave * 4 + i) * 64 + lane;
      int row = ch >> 3;
      gld16(Wf1b + (size_t)(d0 + row) * 1024 + kt * 64 + sw, Bs + ch * 8);
    }
    __syncthreads();
#pragma unroll
    for (int ks = 0; ks < 2; ++ks) {
      const int cx = ks ? cx1 : cx0;
      bf16x8 a[4], bb[8];
#pragma unroll
      for (int t = 0; t < 4; ++t)
        a[t] = *(const bf16x8*)(As + (wm + cl + t * 16) * 64 + cx);
#pragma unroll
      for (int t = 0; t < 8; ++t)
        bb[t] = *(const bf16x8*)(Bs + (cl + t * 16) * 64 + cx);
#pragma unroll
      for (int mt = 0; mt < 4; ++mt)
#pragma unroll
        for (int nt = 0; nt < 8; ++nt)
          acc[mt][nt] = __builtin_amdgcn_mfma_f32_16x16x32_bf16(a[mt], bb[nt], acc[mt][nt], 0, 0, 0);
    }
  }

  // epilogue: plain bf16 store (bias + retrieval handled in ln_relu)
#pragma unroll
  for (int mt = 0; mt < 4; ++mt) {
#pragma unroll
    for (int r = 0; r < 4; ++r) {
      int row = tok0 + wm + mt * 16 + quad * 4 + r;
#pragma unroll
      for (int nt = 0; nt < 8; ++nt) {
        int d = d0 + nt * 16 + cl;
        hb[(size_t)row * 1024 + d] = f2bf(acc[mt][nt][r]);
      }
    }
  }
}

// ---------------------------------------------------------------------------
// ln_relu: h = hb + bf + w0*P[i0] + w1*P[i1] + w2*P[i2];
//          out = ReLU(LN(h) * gamma + beta).  One wave per token.
// grid: 4096 blocks x 256
// ---------------------------------------------------------------------------
__global__ __launch_bounds__(256) void ln_relu_kernel(
    const unsigned short* __restrict__ hb, const float* __restrict__ P,
    const float4* __restrict__ meta, const float* __restrict__ bfv,
    const float* __restrict__ gamma, const float* __restrict__ beta,
    float* __restrict__ out) {
  const int tid = threadIdx.x;
  const int wave = tid >> 6, lane = tid & 63;
  const int t = blockIdx.x * 4 + wave;
  const int dbase = lane * 16;

  float4 mv = meta[t];
  int pk = __float_as_int(mv.w);
  const float* P0 = P + (pk & 255) * 1024 + dbase;
  const float* P1 = P + ((pk >> 8) & 255) * 1024 + dbase;
  const float* P2 = P + ((pk >> 16) & 255) * 1024 + dbase;
  const float* bp = bfv + dbase;

  const unsigned short* hp = hb + (size_t)t * 1024 + dbase;
  u16x8 h0 = *(const u16x8*)(hp);
  u16x8 h1 = *(const u16x8*)(hp + 8);
  float f[16];
#pragma unroll
  for (int j = 0; j < 8; ++j) { f[j] = bf2f(h0[j]); f[8 + j] = bf2f(h1[j]); }
#pragma unroll
  for (int j4 = 0; j4 < 4; ++j4) {
    float4 b4 = *(const float4*)(bp + j4 * 4);
    float4 p0 = *(const float4*)(P0 + j4 * 4);
    float4 p1 = *(const float4*)(P1 + j4 * 4);
    float4 p2 = *(const float4*)(P2 + j4 * 4);
    f[j4 * 4 + 0] += b4.x + mv.x * p0.x + mv.y * p1.x + mv.z * p2.x;
    f[j4 * 4 + 1] += b4.y + mv.x * p0.y + mv.y * p1.y + mv.z * p2.y;
    f[j4 * 4 + 2] += b4.z + mv.x * p0.z + mv.y * p1.z + mv.z * p2.z;
    f[j4 * 4 + 3] += b4.w + mv.x * p0.w + mv.y * p1.w + mv.z * p2.w;
  }
  float s = 0.f, q = 0.f;
#pragma unroll
  for (int j = 0; j < 16; ++j) { s += f[j]; q += f[j] * f[j]; }
#pragma unroll
  for (int off = 32; off; off >>= 1) {
    s += __shfl_xor(s, off);
    q += __shfl_xor(q, off);
  }
  float mean = s * (1.f / 1024.f);
  float var = q * (1.f / 1024.f) - mean * mean;
  float rs = rsqrtf(var + 1e-5f);
  float* op = out + (size_t)t * 1024 + dbase;
#pragma unroll
  for (int j4 = 0; j4 < 4; ++j4) {
    float4 g4 = *(const float4*)(gamma + dbase + j4 * 4);
    float4 e4 = *(const float4*)(beta + dbase + j4 * 4);
    float4 v;
    v.x = fmaxf((f[j4 * 4 + 0] - mean) * rs * g4.x + e4.x, 0.f);
    v.y = fmaxf((f[j4 * 4 + 1] - mean) * rs * g4.y + e4.y, 0.f);
    v.z = fmaxf((f[j4 * 4 + 2] - mean) * rs * g4.z + e4.z, 0.f);
    v.w = fmaxf((f[j4 * 4 + 3] - mean) * rs * g4.w + e4.w, 0.f);
    *(float4*)(op + j4 * 4) = v;
  }
}

// ---------------------------------------------------------------------------
extern "C" void kernel_launch(void* const* d_in, const int* in_sizes, int n_in,
                              void* d_out, int out_size, void* d_ws, size_t ws_size,
                              hipStream_t stream) {
  const float* x     = (const float*)d_in[0];
  const float* memv  = (const float*)d_in[1];
  const float* Wq    = (const float*)d_in[2];
  const float* bq    = (const float*)d_in[3];
  const float* Wf    = (const float*)d_in[4];
  const float* bfv   = (const float*)d_in[5];
  const float* gamma = (const float*)d_in[6];
  const float* beta  = (const float*)d_in[7];
  float* out = (float*)d_out;
  char* ws = (char*)d_ws;

  unsigned short* Wf1b   = (unsigned short*)(ws);              // 2 MB
  unsigned short* Wmb    = (unsigned short*)(ws + 2097152);    // 128 KB
  float*          P      = (float*)(ws + 2228224);             // 256 KB
  float*          sc     = (float*)(ws + 2490368);             // 256 B
  float4*         meta   = (float4*)(ws + 2490624);            // 256 KB
  float*          Wf2T   = (float*)(ws + 2752768);             // 4 MB
  float*          partWm = (float*)(ws + 6947072);             // 2 MB
  float*          partP  = (float*)(ws + 9044224);             // 2 MB
  unsigned short* xb     = (unsigned short*)(ws + 11141376);   // 32 MB
  unsigned short* hb     = (unsigned short*)(ws + 44695808);   // 32 MB
  // total ws usage: 78,250,240 bytes

  hipLaunchKernelGGL(prep_a_kernel, dim3(16705), dim3(256), 0, stream,
                     x, xb, Wf, Wf2T, Wf1b, bq, memv, sc);
  hipLaunchKernelGGL(prep_b_kernel, dim3(256), dim3(256), 0, stream,
                     memv, Wq, Wf2T, partWm, partP);
  hipLaunchKernelGGL(prep_c_kernel, dim3(512), dim3(256), 0, stream,
                     partWm, partP, Wmb, P);
  hipLaunchKernelGGL(sim_topk_kernel, dim3(256), dim3(256), 0, stream,
                     xb, Wmb, sc, meta);
  hipLaunchKernelGGL(gemm_h_kernel, dim3(512), dim3(256), 0, stream,
                     xb, Wf1b, hb);
  hipLaunchKernelGGL(ln_relu_kernel, dim3(4096), dim3(256), 0, stream,
                     hb, P, meta, bfv, gamma, beta, out);
}